// Round 1
// baseline (1192.804 us; speedup 1.0000x reference)
//
#include <hip/hip_runtime.h>
#include <cstdint>
#include <cstddef>

#define HH    128
#define VV    256
#define NB    8
#define NROW  2048        /* NB*VV  rows of h      */
#define NEROW 524288      /* NB*VV*VV rows of e    */
#define PROJ  (NROW*HH)   /* 262144 floats         */
#define EPSV  1e-5f

__device__ inline float4 f4add(float4 a, float4 b) {
    return make_float4(a.x+b.x, a.y+b.y, a.z+b.z, a.w+b.w);
}
__device__ inline float4 f4fma(float4 a, float4 b, float4 c) {  // a*b + c
    return make_float4(fmaf(a.x,b.x,c.x), fmaf(a.y,b.y,c.y),
                       fmaf(a.z,b.z,c.z), fmaf(a.w,b.w,c.w));
}
__device__ inline float4 sig4(float4 x) {
    return make_float4(1.f/(1.f+__expf(-x.x)), 1.f/(1.f+__expf(-x.y)),
                       1.f/(1.f+__expf(-x.z)), 1.f/(1.f+__expf(-x.w)));
}

// ---------------------------------------------------------------------------
// K1: Uh/Vh/Ah/Bh = h @ W^T + b   for 4 weight matrices.
// grid 64, block 256; each block handles 32 rows; h-tile staged in LDS,
// weights streamed from global (L1-resident, 64KB each).
// ---------------------------------------------------------------------------
__global__ __launch_bounds__(256) void k1_proj(
    const float* __restrict__ h,
    const float* __restrict__ Uw, const float* __restrict__ Ub,
    const float* __restrict__ Vw, const float* __restrict__ Vb,
    const float* __restrict__ Aw, const float* __restrict__ Ab,
    const float* __restrict__ Bw, const float* __restrict__ Bb,
    float* __restrict__ ws)
{
    __shared__ float hs[32*136];
    const int t  = threadIdx.x;
    const int R0 = blockIdx.x * 32;
    {
        const float4* src = (const float4*)(h + (size_t)R0*HH);
        #pragma unroll
        for (int ii = 0; ii < 4; ++ii) {
            int idx4 = t + 256*ii;            // 0..1023
            int r = idx4 >> 5, c = idx4 & 31;
            *(float4*)&hs[r*136 + c*4] = src[idx4];
        }
    }
    __syncthreads();
    const int o0 = (t & 15) * 8;              // output column group
    const int jg = t >> 4;                    // 0..15, rows jg*2 .. jg*2+1
    const float* Ws[4] = {Uw, Vw, Aw, Bw};
    const float* Bs[4] = {Ub, Vb, Ab, Bb};
    #pragma unroll 1
    for (int m = 0; m < 4; ++m) {
        const float* __restrict__ W = Ws[m];
        float acc[2][8];
        #pragma unroll
        for (int jj = 0; jj < 2; ++jj)
            #pragma unroll
            for (int d = 0; d < 8; ++d) acc[jj][d] = 0.f;
        for (int k4 = 0; k4 < 32; ++k4) {
            float4 w[8];
            #pragma unroll
            for (int d = 0; d < 8; ++d)
                w[d] = *(const float4*)(W + (size_t)(o0+d)*HH + k4*4);
            #pragma unroll
            for (int jj = 0; jj < 2; ++jj) {
                float4 ev = *(const float4*)&hs[(jg*2+jj)*136 + k4*4];
                #pragma unroll
                for (int d = 0; d < 8; ++d)
                    acc[jj][d] += ev.x*w[d].x + ev.y*w[d].y
                                + ev.z*w[d].z + ev.w*w[d].w;
            }
        }
        float4 b0 = *(const float4*)(Bs[m] + o0);
        float4 b1 = *(const float4*)(Bs[m] + o0 + 4);
        float* outp = ws + (size_t)m * PROJ;
        #pragma unroll
        for (int jj = 0; jj < 2; ++jj) {
            int r = R0 + jg*2 + jj;
            float4 v0 = f4add(make_float4(acc[jj][0],acc[jj][1],acc[jj][2],acc[jj][3]), b0);
            float4 v1 = f4add(make_float4(acc[jj][4],acc[jj][5],acc[jj][6],acc[jj][7]), b1);
            *(float4*)(outp + (size_t)r*HH + o0)     = v0;
            *(float4*)(outp + (size_t)r*HH + o0 + 4) = v1;
        }
    }
}

// ---------------------------------------------------------------------------
// K2: per (b,i) block over all j:
//   Ce = e_row @ Cw^T ; e_new = Ce + Cb + Ah[b,j] + Bh[b,i]  (stored to out_e)
//   gate = sigmoid(e_new); agg[b,i] = sum_j (graph? 0 : gate*Vh[b,j])
//   e-batchnorm partial sums (per-channel) via atomics.
// grid 2048, block 256. Thread tile: 8 j x 8 o. e-tile (128 rows) in LDS.
// ---------------------------------------------------------------------------
__global__ __launch_bounds__(256) void k2_main(
    const float* __restrict__ e,
    const int*   __restrict__ graph,
    const float* __restrict__ Cw, const float* __restrict__ Cb,
    const float* __restrict__ ws,
    float* __restrict__ agg_out,
    float* __restrict__ esum, float* __restrict__ esumsq,
    float* __restrict__ e_new_out)
{
    __shared__ float lds[128*136];            // 69.6 KB -> 2 blocks/CU
    const int t  = threadIdx.x;
    const int bi = blockIdx.x;                // b*V + i
    const int b  = bi >> 8;
    const int o0 = (t & 15) * 8;
    const int jg = t >> 4;                    // 0..15
    const float* __restrict__ Vh = ws + (size_t)PROJ;
    const float* __restrict__ Ah = ws + 2*(size_t)PROJ;
    const float* __restrict__ Bh = ws + 3*(size_t)PROJ;
    const float4 Bh0 = *(const float4*)(Bh + (size_t)bi*HH + o0);
    const float4 Bh1 = *(const float4*)(Bh + (size_t)bi*HH + o0 + 4);
    const float4 Cb0 = *(const float4*)(Cb + o0);
    const float4 Cb1 = *(const float4*)(Cb + o0 + 4);
    float4 agg0 = make_float4(0,0,0,0), agg1 = agg0;
    float4 se0 = agg0, se1 = agg0, sq0 = agg0, sq1 = agg0;

    #pragma unroll 1
    for (int p = 0; p < 2; ++p) {
        __syncthreads();
        const float4* src = (const float4*)(e + ((size_t)bi*VV + p*128)*HH);
        #pragma unroll
        for (int ii = 0; ii < 16; ++ii) {
            int idx4 = t + 256*ii;            // 0..4095
            int r = idx4 >> 5, c = idx4 & 31;
            *(float4*)&lds[r*136 + c*4] = src[idx4];
        }
        __syncthreads();

        float acc[8][8];
        #pragma unroll
        for (int jj = 0; jj < 8; ++jj)
            #pragma unroll
            for (int d = 0; d < 8; ++d) acc[jj][d] = 0.f;

        for (int k4 = 0; k4 < 32; ++k4) {
            float4 w[8];
            #pragma unroll
            for (int d = 0; d < 8; ++d)
                w[d] = *(const float4*)(Cw + (size_t)(o0+d)*HH + k4*4);
            #pragma unroll
            for (int jj = 0; jj < 8; ++jj) {
                float4 ev = *(const float4*)&lds[(jg*8+jj)*136 + k4*4];
                #pragma unroll
                for (int d = 0; d < 8; ++d)
                    acc[jj][d] += ev.x*w[d].x + ev.y*w[d].y
                                + ev.z*w[d].z + ev.w*w[d].w;
            }
        }

        #pragma unroll
        for (int jj = 0; jj < 8; ++jj) {
            int j = p*128 + jg*8 + jj;
            size_t rowA = (size_t)(b*VV + j) * HH;
            size_t rowE = ((size_t)bi*VV + j) * HH;
            float4 A0 = *(const float4*)(Ah + rowA + o0);
            float4 A1 = *(const float4*)(Ah + rowA + o0 + 4);
            float4 V0 = *(const float4*)(Vh + rowA + o0);
            float4 V1 = *(const float4*)(Vh + rowA + o0 + 4);
            int gmask = graph[(size_t)bi*VV + j];
            float4 en0 = f4add(f4add(make_float4(acc[jj][0],acc[jj][1],acc[jj][2],acc[jj][3]), A0),
                               f4add(Bh0, Cb0));
            float4 en1 = f4add(f4add(make_float4(acc[jj][4],acc[jj][5],acc[jj][6],acc[jj][7]), A1),
                               f4add(Bh1, Cb1));
            *(float4*)(e_new_out + rowE + o0)     = en0;
            *(float4*)(e_new_out + rowE + o0 + 4) = en1;
            se0 = f4add(se0, en0);        se1 = f4add(se1, en1);
            sq0 = f4fma(en0, en0, sq0);   sq1 = f4fma(en1, en1, sq1);
            if (!gmask) {
                agg0 = f4fma(sig4(en0), V0, agg0);
                agg1 = f4fma(sig4(en1), V1, agg1);
            }
        }
    }

    // cross-group reduction (16 jg groups) for agg / sum / sumsq
    __syncthreads();
    *(float4*)&lds[0*2048 + jg*128 + o0]     = agg0;
    *(float4*)&lds[0*2048 + jg*128 + o0 + 4] = agg1;
    *(float4*)&lds[1*2048 + jg*128 + o0]     = se0;
    *(float4*)&lds[1*2048 + jg*128 + o0 + 4] = se1;
    *(float4*)&lds[2*2048 + jg*128 + o0]     = sq0;
    *(float4*)&lds[2*2048 + jg*128 + o0 + 4] = sq1;
    __syncthreads();
    if (t < 128) {
        float sa = 0.f, ss = 0.f, s2 = 0.f;
        #pragma unroll
        for (int g = 0; g < 16; ++g) {
            sa += lds[       g*128 + t];
            ss += lds[2048 + g*128 + t];
            s2 += lds[4096 + g*128 + t];
        }
        agg_out[(size_t)bi*HH + t] = sa;
        atomicAdd(&esum[t],   ss);
        atomicAdd(&esumsq[t], s2);
    }
}

// ---------------------------------------------------------------------------
// K3a: h_new = Uh + agg, plus per-channel sum/sumsq. grid 128, block 256.
// ---------------------------------------------------------------------------
__global__ __launch_bounds__(256) void k3a_hnew(
    const float* __restrict__ Uh, const float* __restrict__ agg,
    float* __restrict__ hnew, float* __restrict__ hsum, float* __restrict__ hsumsq)
{
    __shared__ float red[512];
    const int t = threadIdx.x;
    const int o = t & 127;
    const int g = t >> 7;
    const int R0 = blockIdx.x * 16;
    float s = 0.f, s2 = 0.f;
    #pragma unroll
    for (int rr = 0; rr < 8; ++rr) {
        size_t idx = (size_t)(R0 + g*8 + rr)*HH + o;
        float v = Uh[idx] + agg[idx];
        hnew[idx] = v;
        s += v; s2 += v*v;
    }
    red[t] = s; red[256 + t] = s2;
    __syncthreads();
    if (t < 128) {
        atomicAdd(&hsum[o],   red[t]     + red[t + 128]);
        atomicAdd(&hsumsq[o], red[256+t] + red[256 + t + 128]);
    }
}

// ---------------------------------------------------------------------------
// K3b: fold batchnorm into per-channel affine (a,c) for h and e. 1x128.
// stats layout: [esum|esumsq|hsum|hsumsq|a_h|c_h|a_e|c_e] each 128 floats
// ---------------------------------------------------------------------------
__global__ void k3b_coef(const float* __restrict__ st, float* __restrict__ coef,
    const float* __restrict__ gh, const float* __restrict__ bh,
    const float* __restrict__ ge, const float* __restrict__ be)
{
    int o = threadIdx.x;
    float es = st[o], eq = st[128+o], hs = st[256+o], hq = st[384+o];
    float me = es * (1.f/(float)NEROW);
    float ve = eq * (1.f/(float)NEROW) - me*me;
    float ae = ge[o] * rsqrtf(ve + EPSV);
    float ce = be[o] - me*ae;
    float mh = hs * (1.f/(float)NROW);
    float vh = hq * (1.f/(float)NROW) - mh*mh;
    float ah = gh[o] * rsqrtf(vh + EPSV);
    float ch = bh[o] - mh*ah;
    coef[o] = ah; coef[128+o] = ch; coef[256+o] = ae; coef[384+o] = ce;
}

// ---------------------------------------------------------------------------
// K3c: h_out = h_in + relu(a*h_new + c). grid 256, block 256, 1 float4 each.
// ---------------------------------------------------------------------------
__global__ __launch_bounds__(256) void k3c_hout(
    const float* __restrict__ h_in, const float* __restrict__ hnew,
    const float* __restrict__ coef, float* __restrict__ out_h)
{
    int idx = blockIdx.x*256 + threadIdx.x;       // < 65536
    int o4 = (idx & 31) * 4;
    float4 a = *(const float4*)(coef + o4);
    float4 c = *(const float4*)(coef + 128 + o4);
    float4 v = ((const float4*)hnew)[idx];
    float4 x = ((const float4*)h_in)[idx];
    float4 r;
    r.x = x.x + fmaxf(fmaf(a.x, v.x, c.x), 0.f);
    r.y = x.y + fmaxf(fmaf(a.y, v.y, c.y), 0.f);
    r.z = x.z + fmaxf(fmaf(a.z, v.z, c.z), 0.f);
    r.w = x.w + fmaxf(fmaf(a.w, v.w, c.w), 0.f);
    ((float4*)out_h)[idx] = r;
}

// ---------------------------------------------------------------------------
// K4: e_out = e_in + relu(a_e*e_new + c_e), in-place over e_new region.
// grid-stride float4; stride % 32 == 0 keeps channel group invariant.
// ---------------------------------------------------------------------------
__global__ __launch_bounds__(256) void k4_eout(
    const float* __restrict__ e_in, const float* __restrict__ coef,
    float* __restrict__ e_io)
{
    const size_t total4 = (size_t)NEROW * HH / 4;     // 16777216
    size_t idx = (size_t)blockIdx.x * 256 + threadIdx.x;
    const size_t stride = (size_t)gridDim.x * 256;    // 2M, % 32 == 0
    const int o4 = ((int)(idx & 31)) * 4;
    const float4 a = *(const float4*)(coef + 256 + o4);
    const float4 c = *(const float4*)(coef + 384 + o4);
    const float4* ein4 = (const float4*)e_in;
    float4* eio4 = (float4*)e_io;
    for (; idx < total4; idx += stride) {
        float4 v = eio4[idx];
        float4 x = ein4[idx];
        float4 r;
        r.x = x.x + fmaxf(fmaf(a.x, v.x, c.x), 0.f);
        r.y = x.y + fmaxf(fmaf(a.y, v.y, c.y), 0.f);
        r.z = x.z + fmaxf(fmaf(a.z, v.z, c.z), 0.f);
        r.w = x.w + fmaxf(fmaf(a.w, v.w, c.w), 0.f);
        eio4[idx] = r;
    }
}

// ---------------------------------------------------------------------------
extern "C" void kernel_launch(void* const* d_in, const int* in_sizes, int n_in,
                              void* d_out, int out_size, void* d_ws, size_t ws_size,
                              hipStream_t stream)
{
    (void)in_sizes; (void)n_in; (void)out_size; (void)ws_size;
    const float* h     = (const float*)d_in[0];
    const float* e     = (const float*)d_in[1];
    const int*   graph = (const int*)  d_in[2];
    const float* Uw = (const float*)d_in[3];
    const float* Ub = (const float*)d_in[4];
    const float* Vw = (const float*)d_in[5];
    const float* Vb = (const float*)d_in[6];
    const float* Aw = (const float*)d_in[7];
    const float* Ab = (const float*)d_in[8];
    const float* Bw = (const float*)d_in[9];
    const float* Bb = (const float*)d_in[10];
    const float* Cw = (const float*)d_in[11];
    const float* Cb = (const float*)d_in[12];
    const float* gamma_h = (const float*)d_in[13];
    const float* beta_h  = (const float*)d_in[14];
    const float* gamma_e = (const float*)d_in[15];
    const float* beta_e  = (const float*)d_in[16];

    float* out_h = (float*)d_out;
    float* out_e = out_h + (size_t)NROW * HH;     // e_new scratch, then e_out

    float* ws    = (float*)d_ws;
    float* Uh    = ws;                            // [0,PROJ) U; then V,A,B
    float* aggp  = ws + 4*(size_t)PROJ;
    float* hnew  = ws + 5*(size_t)PROJ;
    float* stats = ws + 6*(size_t)PROJ;           // 512 floats sums + 512 coef
    float* coef  = stats + 512;

    hipMemsetAsync(stats, 0, 512*sizeof(float), stream);
    k1_proj<<<64, 256, 0, stream>>>(h, Uw,Ub, Vw,Vb, Aw,Ab, Bw,Bb, ws);
    k2_main<<<2048, 256, 0, stream>>>(e, graph, Cw, Cb, ws, aggp,
                                      stats, stats+128, out_e);
    k3a_hnew<<<128, 256, 0, stream>>>(Uh, aggp, hnew, stats+256, stats+384);
    k3b_coef<<<1, 128, 0, stream>>>(stats, coef, gamma_h, beta_h, gamma_e, beta_e);
    k3c_hout<<<256, 256, 0, stream>>>(h, hnew, coef, out_h);
    k4_eout<<<8192, 256, 0, stream>>>(e, coef, out_e);
}